// Round 2
// baseline (1393.374 us; speedup 1.0000x reference)
//
#include <hip/hip_runtime.h>

// CauRecNet: 2-layer LSTM, B=131072 x T=15, i8-pair (14-bit fixed point) MFMA.
// prequant kernel: weights -> per-row-scaled i8 hi/lo fragments in d_ws.
// main kernel: 64 rows/block, 8 waves; states as i8-pair arrays in LDS,
// 3-pass i8 MFMA (hi*hi -> accA, hi*lo + lo*hi -> accB), exact i32 accum.

typedef int   i32x4 __attribute__((ext_vector_type(4)));
typedef float f32x4 __attribute__((ext_vector_type(4)));

#define DEV static __device__ __forceinline__

#if __has_builtin(__builtin_amdgcn_exp2f)
DEV float fexp2(float x){ return __builtin_amdgcn_exp2f(x); }
#else
DEV float fexp2(float x){ return exp2f(x); }
#endif
#if __has_builtin(__builtin_amdgcn_rcpf)
DEV float frcp(float x){ return __builtin_amdgcn_rcpf(x); }
#else
DEV float frcp(float x){ return 1.0f/x; }
#endif

DEV float fsig(float x){ return frcp(1.0f + fexp2(x * -1.44269504f)); }
DEV float ftanh(float x){ return 1.0f - 2.0f*frcp(1.0f + fexp2(x * 2.88539008f)); }

#define MFMA64(A,B,C) __builtin_amdgcn_mfma_i32_16x16x64_i8(A,B,C,0,0,0)
#define MFMA32(A,B,C) __builtin_amdgcn_mfma_i32_16x16x32_i8(A,B,C,0,0,0)

constexpr int T = 15, F = 12, CS = 96;
constexpr int R = 64;

// d_ws layout (bytes)
constexpr int Q1OFF  = 0;        // W1 frags [8w][4g][3ks][2sp][64][16] = 196608
constexpr int Q0OFF  = 196608;   // W0 frags [4grp][4g]{x:2sp*512 | h:2sp*1024} = 49152
constexpr int QF2OFF = 245760;   // fc2 frags [8][2ks][2sp][64][16] = 32768
constexpr int QF1OFF = 278528;   // fc1 frags [4][2ks][2sp][64][16] = 16384
constexpr int S1OFF  = 294912;   // f32[512]
constexpr int S0OFF  = 296960;   // f32[256]
constexpr int SF2OFF = 297984;   // f32[128]
constexpr int SF1OFF = 298496;   // f32[64]

constexpr float QM   = 16128.0f;        // h grid (|h|<=1)
constexpr float QMX  = 2016.0f;         // x / cs grid = QM/8  (|x| <= 8)
constexpr float HINV = 1.0f/16128.0f;

// ---------------- weight pre-quantization ----------------
__global__ __launch_bounds__(64) void prequant(
    const float* __restrict__ fc1w, const float* __restrict__ fc2w,
    const float* __restrict__ w0i,  const float* __restrict__ w0h,
    const float* __restrict__ w1i,  const float* __restrict__ w1h,
    char* __restrict__ ws)
{
  const int r = blockIdx.x, j = threadIdx.x;
  float v[3] = {0.f, 0.f, 0.f};
  int   kk[3] = {-1, -1, -1};
  int type, n;
  if (r < 512){ type = 0; n = r; }
  else if (r < 768){ type = 1; n = r - 512; }
  else if (r < 896){ type = 2; n = r - 768; }
  else { type = 3; n = r - 896; }

  if (type == 0){               // W1 row n: k-space 192 = [w_ih 64 | w_hh 128]
    for (int c = 0; c < 3; ++c){
      int k = j + c*64; kk[c] = k;
      v[c] = (k < 64) ? w1i[n*64 + k] : w1h[n*128 + (k - 64)];
    }
  } else if (type == 1){        // W0 row n: k-space 96 = [x 32 (12 real) | h 64]
    kk[0] = j;
    v[0] = (j < 32) ? ((j < 12) ? w0i[n*12 + j] : 0.f) : w0h[n*64 + (j - 32)];
    if (j < 32){ kk[1] = 64 + j; v[1] = w0h[n*64 + (32 + j)]; }
  } else {                      // fc row n: k-space 128 (96 real)
    const float* fw = (type == 2) ? fc2w : fc1w;
    for (int c = 0; c < 2; ++c){
      int k = j + c*64; kk[c] = k;
      v[c] = (k < 96) ? fw[n*CS + k] : 0.f;
    }
  }
  float m = fmaxf(fmaxf(fabsf(v[0]), fabsf(v[1])), fabsf(v[2]));
  #pragma unroll
  for (int d = 32; d; d >>= 1) m = fmaxf(m, __shfl_xor(m, d));
  float s   = (m > 0.f) ? (m / 16120.0f) : 1.0f;
  float inv = (m > 0.f) ? (16120.0f / m) : 0.0f;
  if (j == 0){
    float* sp = (float*)(ws + (type==0 ? S1OFF : type==1 ? S0OFF : type==2 ? SF2OFF : SF1OFF));
    sp[n] = s;
  }
  const int lr = n & 15;
  #pragma unroll
  for (int c = 0; c < 3; ++c){
    int k = kk[c];
    if (k < 0) continue;
    float q  = rintf(v[c] * inv);
    float hf = rintf(q * 0.0078125f);
    int hi = (int)hf, lo = (int)(q - hf*128.0f);
    long offh, offl;
    if (type == 0){
      int g = n >> 7, wv = (n & 127) >> 4;
      int ks = k >> 6, lg = (k >> 4) & 3, jj = k & 15, lane = lg*16 + lr;
      long base = Q1OFF + (((long)((wv*4+g)*3+ks)*2*64) + lane)*16 + jj;
      offh = base; offl = base + 1024;
    } else if (type == 1){
      int g = n >> 6, grp = (n & 63) >> 4;
      long b0 = Q0OFF + (long)(grp*4+g)*3072;
      if (k < 32){ int lg = (k>>3)&3, jj = k&7, lane = lg*16+lr;
        offh = b0 + lane*8 + jj; offl = offh + 512;
      } else { int kh = k-32, lg = kh>>4, jj = kh&15, lane = lg*16+lr;
        offh = b0 + 1024 + lane*16 + jj; offl = offh + 1024;
      }
    } else {
      int ks = k >> 6, lg = (k>>4)&3, jj = k&15, lane = lg*16+lr;
      int grp = n >> 4;
      long base = (type==2 ? QF2OFF : QF1OFF) + ((long)((grp*2+ks)*2)*64 + lane)*16 + jj;
      offh = base; offl = base + 1024;
    }
    ws[offh] = (char)hi; ws[offl] = (char)lo;
  }
}

// ---------------- main recurrence kernel ----------------
__global__ __launch_bounds__(512, 2) void caurec(
    const float* __restrict__ x,    const float* __restrict__ cs,
    const float* __restrict__ fc1b, const float* __restrict__ fc2b,
    const float* __restrict__ b0i,  const float* __restrict__ b0h,
    const float* __restrict__ b1i,  const float* __restrict__ b1h,
    const float* __restrict__ d1w,  const float* __restrict__ d1b,
    const float* __restrict__ d2w,  const float* __restrict__ d2b,
    const char* __restrict__ ws,    float* __restrict__ out)
{
  // xh0: per-row 128B: [0,32) x (12 real), [32,96) h0, [96,128) zero
  // xh1: per-row 256B: [0,64) h0n, [64,192) h1, [192,256) zero / cs-staging at [128,224)
  __shared__ char xh0h[64*128], xh0l[64*128];
  __shared__ char xh1h[64*256], xh1l[64*256];
  __shared__ float wEff[132];

  const int tid  = threadIdx.x;
  const int wave = tid >> 6, lane = tid & 63, lr = lane & 15, lg = lane >> 4;
  const int n0   = (wave & 3) * 16, mB0 = (wave >> 2) * 32, n1 = wave * 16;
  const int grp  = wave & 3;
  const int rowBase = blockIdx.x * R;

  auto a0 = [&](int row, int off){ return row*128 + (off ^ ((row & 7) << 4)); };
  auto a1 = [&](int row, int off){ return row*256 + (off ^ ((row & 7) << 4)); };

  // zero LDS
  #pragma unroll
  for (int i = tid; i < 64*128/4; i += 512){ ((unsigned*)xh0h)[i] = 0u; ((unsigned*)xh0l)[i] = 0u; }
  #pragma unroll
  for (int i = tid; i < 64*256/4; i += 512){ ((unsigned*)xh1h)[i] = 0u; ((unsigned*)xh1l)[i] = 0u; }
  __syncthreads();

  auto stageX = [&](int t){
    if (tid < 192){
      int r = tid / 3, q4 = tid - (tid/3)*3;
      float4 v = *(const float4*)&x[((size_t)(rowBase + r)*T + t)*F + q4*4];
      float vv[4] = {v.x, v.y, v.z, v.w};
      unsigned hw = 0u, lw = 0u;
      #pragma unroll
      for (int e = 0; e < 4; ++e){
        float q  = fminf(16128.f, fmaxf(-16128.f, rintf(vv[e]*QMX)));
        float hf = rintf(q * 0.0078125f);
        int hi = (int)hf, lo = (int)(q - hf*128.f);
        hw |= (unsigned)(hi & 255) << (8*e);
        lw |= (unsigned)(lo & 255) << (8*e);
      }
      int ad = a0(r, q4*4);
      *(unsigned*)&xh0h[ad] = hw; *(unsigned*)&xh0l[ad] = lw;
    }
  };

  // stage cs (into xh1 bytes [128,224)), x_0, wEff
  #pragma unroll
  for (int it = 0; it < 3; ++it){
    int u = tid + it*512;
    int r = u / 24, q4 = u - r*24;
    float4 v = *(const float4*)&cs[(size_t)(rowBase + r)*CS + q4*4];
    float vv[4] = {v.x, v.y, v.z, v.w};
    unsigned hw = 0u, lw = 0u;
    #pragma unroll
    for (int e = 0; e < 4; ++e){
      float q  = fminf(16128.f, fmaxf(-16128.f, rintf(vv[e]*QMX)));
      float hf = rintf(q * 0.0078125f);
      int hi = (int)hf, lo = (int)(q - hf*128.f);
      hw |= (unsigned)(hi & 255) << (8*e);
      lw |= (unsigned)(lo & 255) << (8*e);
    }
    int ad = a1(r, 128 + q4*4);
    *(unsigned*)&xh1h[ad] = hw; *(unsigned*)&xh1l[ad] = lw;
  }
  stageX(0);
  if (tid < 128){
    float s = 0.f;
    for (int a = 0; a < 64; ++a) s += d2w[a] * d1w[a*128 + tid];
    wEff[tid] = s;
  } else if (tid == 128){
    float s = 0.f;
    for (int a = 0; a < 64; ++a) s += d2w[a] * d1b[a];
    wEff[128] = s + d2b[0];
  }
  __syncthreads();

  // persistent weight fragments
  i32x4 WB1[4][3][2];
  #pragma unroll
  for (int g = 0; g < 4; ++g)
    #pragma unroll
    for (int ks = 0; ks < 3; ++ks)
      #pragma unroll
      for (int sp = 0; sp < 2; ++sp)
        WB1[g][ks][sp] = *(const i32x4*)(ws + Q1OFF + ((long)(((wave*4+g)*3+ks)*2+sp)*64 + lane)*16);
  i32x4 WB0h[4][2]; long WB0x[4][2];
  #pragma unroll
  for (int g = 0; g < 4; ++g){
    const char* b0 = ws + Q0OFF + (long)(grp*4+g)*3072;
    #pragma unroll
    for (int sp = 0; sp < 2; ++sp){
      WB0x[g][sp] = *(const long*)(b0 + sp*512 + lane*8);
      WB0h[g][sp] = *(const i32x4*)(b0 + 1024 + sp*1024 + lane*16);
    }
  }
  const float* S1  = (const float*)(ws + S1OFF);
  const float* S0  = (const float*)(ws + S0OFF);
  float s1c[4], s0c[4], b1v[4], b0v[4];
  #pragma unroll
  for (int g = 0; g < 4; ++g){
    s1c[g] = S1[g*128 + n1 + lr] * HINV;
    b1v[g] = b1i[g*128 + n1 + lr] + b1h[g*128 + n1 + lr];
    s0c[g] = S0[g*64 + n0 + lr] * HINV;
    b0v[g] = b0i[g*64 + n0 + lr] + b0h[g*64 + n0 + lr];
  }

  // init GEMMs: c1 = cs@fc2w^T + fc2b ; c0 = cs@fc1w^T + fc1b
  f32x4 c1r[4], c0r[2];
  {
    float sf2 = ((const float*)(ws + SF2OFF))[n1 + lr] * HINV * 8.0f;
    float bb2 = fc2b[n1 + lr];
    #pragma unroll
    for (int mt = 0; mt < 4; ++mt){
      i32x4 aA = {0,0,0,0}, aB = {0,0,0,0};
      #pragma unroll
      for (int ks = 0; ks < 2; ++ks){
        int ad = a1(mt*16 + lr, 128 + ks*64 + lg*16);
        i32x4 Ah = *(const i32x4*)&xh1h[ad];
        i32x4 Al = *(const i32x4*)&xh1l[ad];
        i32x4 Bh = *(const i32x4*)(ws + QF2OFF + ((long)((wave*2+ks)*2+0)*64 + lane)*16);
        i32x4 Bl = *(const i32x4*)(ws + QF2OFF + ((long)((wave*2+ks)*2+1)*64 + lane)*16);
        aA = MFMA64(Ah, Bh, aA); aB = MFMA64(Ah, Bl, aB); aB = MFMA64(Al, Bh, aB);
      }
      #pragma unroll
      for (int e = 0; e < 4; ++e)
        c1r[mt][e] = (16384.f*(float)aA[e] + 128.f*(float)aB[e])*sf2 + bb2;
    }
    float sf1 = ((const float*)(ws + SF1OFF))[n0 + lr] * HINV * 8.0f;
    float bb1 = fc1b[n0 + lr];
    #pragma unroll
    for (int mt = 0; mt < 2; ++mt){
      i32x4 aA = {0,0,0,0}, aB = {0,0,0,0};
      #pragma unroll
      for (int ks = 0; ks < 2; ++ks){
        int ad = a1(mB0 + mt*16 + lr, 128 + ks*64 + lg*16);
        i32x4 Ah = *(const i32x4*)&xh1h[ad];
        i32x4 Al = *(const i32x4*)&xh1l[ad];
        i32x4 Bh = *(const i32x4*)(ws + QF1OFF + ((long)((grp*2+ks)*2+0)*64 + lane)*16);
        i32x4 Bl = *(const i32x4*)(ws + QF1OFF + ((long)((grp*2+ks)*2+1)*64 + lane)*16);
        aA = MFMA64(Ah, Bh, aA); aB = MFMA64(Ah, Bl, aB); aB = MFMA64(Al, Bh, aB);
      }
      #pragma unroll
      for (int e = 0; e < 4; ++e)
        c0r[mt][e] = (16384.f*(float)aA[e] + 128.f*(float)aB[e])*sf1 + bb1;
    }
  }
  __syncthreads();
  // re-zero cs staging region (becomes h1-region zeros for t=0)
  #pragma unroll
  for (int i = tid; i < 64*24; i += 512){
    int r = i / 24, w = i - r*24;
    int ad = a1(r, 128 + w*4);
    *(unsigned*)&xh1h[ad] = 0u; *(unsigned*)&xh1l[ad] = 0u;
  }
  __syncthreads();

  // ---- main recurrence ----
  for (int t = 0; t < T; ++t){
    // Phase A: L0 gates
    unsigned h0hw[2], h0lw[2];
    #pragma unroll
    for (int mt = 0; mt < 2; ++mt){
      int row = mB0 + mt*16 + lr;
      long  Xh = *(const long*)&xh0h[a0(row, lg*8)];
      long  Xl = *(const long*)&xh0l[a0(row, lg*8)];
      i32x4 Hh = *(const i32x4*)&xh0h[a0(row, 32 + lg*16)];
      i32x4 Hl = *(const i32x4*)&xh0l[a0(row, 32 + lg*16)];
      f32x4 gate[4];
      #pragma unroll
      for (int g = 0; g < 4; ++g){
        i32x4 z = {0,0,0,0};
        i32x4 hA = MFMA64(Hh, WB0h[g][0], z);
        i32x4 hB = MFMA64(Hh, WB0h[g][1], z);
        hB = MFMA64(Hl, WB0h[g][0], hB);
        i32x4 xA = MFMA32(Xh, WB0x[g][0], z);
        i32x4 xB = MFMA32(Xh, WB0x[g][1], z);
        xB = MFMA32(Xl, WB0x[g][0], xB);
        #pragma unroll
        for (int e = 0; e < 4; ++e)
          gate[g][e] = ((16384.f*(float)hA[e] + 128.f*(float)hB[e])
                 + 8.f*(16384.f*(float)xA[e] + 128.f*(float)xB[e]))*s0c[g] + b0v[g];
      }
      unsigned hw = 0u, lw = 0u;
      #pragma unroll
      for (int e = 0; e < 4; ++e){
        float gi = fsig(gate[0][e]), gf = fsig(gate[1][e]);
        float gg = ftanh(gate[2][e]), go = fsig(gate[3][e]);
        float tmp = gf*c0r[mt][e] + gi*gg;
        float h   = go*ftanh(tmp);
        c0r[mt][e] += tmp;
        float q  = rintf(h*QM);
        float hf = rintf(q*0.0078125f);
        int hi = (int)hf, lo = (int)(q - hf*128.f);
        hw |= (unsigned)(hi & 255) << (8*e);
        lw |= (unsigned)(lo & 255) << (8*e);
      }
      h0hw[mt] = hw; h0lw[mt] = lw;
    }
    __syncthreads();   // A: all reads of xh0 done
    #pragma unroll
    for (int mt = 0; mt < 2; ++mt)
      #pragma unroll
      for (int e = 0; e < 4; ++e){
        int row = mB0 + mt*16 + lg*4 + e;
        char hb = (char)(h0hw[mt] >> (8*e));
        char lb = (char)(h0lw[mt] >> (8*e));
        xh0h[a0(row, 32 + n0 + lr)] = hb;  xh0l[a0(row, 32 + n0 + lr)] = lb;
        xh1h[a1(row, n0 + lr)] = hb;       xh1l[a1(row, n0 + lr)] = lb;
      }
    if (t + 1 < T) stageX(t + 1);
    __syncthreads();   // B: h0n + x_{t+1} visible

    // Phase B: L1 gates
    unsigned h1hw[4], h1lw[4];
    #pragma unroll
    for (int mt = 0; mt < 4; ++mt){
      i32x4 aA[4], aB[4];
      #pragma unroll
      for (int g = 0; g < 4; ++g){ aA[g] = i32x4{0,0,0,0}; aB[g] = i32x4{0,0,0,0}; }
      #pragma unroll
      for (int ks = 0; ks < 3; ++ks){
        int ad = a1(mt*16 + lr, ks*64 + lg*16);
        i32x4 Hh = *(const i32x4*)&xh1h[ad];
        i32x4 Hl = *(const i32x4*)&xh1l[ad];
        #pragma unroll
        for (int g = 0; g < 4; ++g){
          aA[g] = MFMA64(Hh, WB1[g][ks][0], aA[g]);
          aB[g] = MFMA64(Hh, WB1[g][ks][1], aB[g]);
          aB[g] = MFMA64(Hl, WB1[g][ks][0], aB[g]);
        }
      }
      unsigned hw = 0u, lw = 0u;
      #pragma unroll
      for (int e = 0; e < 4; ++e){
        float ai = (16384.f*(float)aA[0][e] + 128.f*(float)aB[0][e])*s1c[0] + b1v[0];
        float af = (16384.f*(float)aA[1][e] + 128.f*(float)aB[1][e])*s1c[1] + b1v[1];
        float ag = (16384.f*(float)aA[2][e] + 128.f*(float)aB[2][e])*s1c[2] + b1v[2];
        float ao = (16384.f*(float)aA[3][e] + 128.f*(float)aB[3][e])*s1c[3] + b1v[3];
        float gi = fsig(ai), gf = fsig(af), gg = ftanh(ag), go = fsig(ao);
        float tmp = gf*c1r[mt][e] + gi*gg;
        float h   = go*ftanh(tmp);
        c1r[mt][e] += tmp;
        float q  = rintf(h*QM);
        float hf = rintf(q*0.0078125f);
        int hi = (int)hf, lo = (int)(q - hf*128.f);
        hw |= (unsigned)(hi & 255) << (8*e);
        lw |= (unsigned)(lo & 255) << (8*e);
      }
      h1hw[mt] = hw; h1lw[mt] = lw;
    }
    __syncthreads();   // C: all reads of xh1 done
    #pragma unroll
    for (int mt = 0; mt < 4; ++mt)
      #pragma unroll
      for (int e = 0; e < 4; ++e){
        int row = mt*16 + lg*4 + e;
        xh1h[a1(row, 64 + n1 + lr)] = (char)(h1hw[mt] >> (8*e));
        xh1l[a1(row, 64 + n1 + lr)] = (char)(h1lw[mt] >> (8*e));
      }
    __syncthreads();   // D
  }

  // epilogue: pred = h1 . w_eff + b_eff
  {
    int r = tid >> 3, s = tid & 7;
    float sum = 0.f;
    #pragma unroll
    for (int cc = 0; cc < 16; ++cc){
      int c = s*16 + cc;
      int ad = a1(r, 64 + c);
      float hq = 128.f*(float)(signed char)xh1h[ad] + (float)(signed char)xh1l[ad];
      sum += hq * HINV * wEff[c];
    }
    sum += __shfl_down(sum, 4);
    sum += __shfl_down(sum, 2);
    sum += __shfl_down(sum, 1);
    if (s == 0) out[rowBase + r] = sum + wEff[128];
  }
}

extern "C" void kernel_launch(void* const* d_in, const int* in_sizes, int n_in,
                              void* d_out, int out_size, void* d_ws, size_t ws_size,
                              hipStream_t stream) {
  const float* x    = (const float*)d_in[0];
  const float* cs   = (const float*)d_in[1];
  const float* fc1w = (const float*)d_in[2];
  const float* fc1b = (const float*)d_in[3];
  const float* fc2w = (const float*)d_in[4];
  const float* fc2b = (const float*)d_in[5];
  const float* w0i  = (const float*)d_in[6];
  const float* w0h  = (const float*)d_in[7];
  const float* b0i  = (const float*)d_in[8];
  const float* b0h  = (const float*)d_in[9];
  const float* w1i  = (const float*)d_in[10];
  const float* w1h  = (const float*)d_in[11];
  const float* b1i  = (const float*)d_in[12];
  const float* b1h  = (const float*)d_in[13];
  const float* d1w  = (const float*)d_in[14];
  const float* d1b  = (const float*)d_in[15];
  const float* d2w  = (const float*)d_in[16];
  const float* d2b  = (const float*)d_in[17];

  char* ws = (char*)d_ws;
  prequant<<<960, 64, 0, stream>>>(fc1w, fc2w, w0i, w0h, w1i, w1h, ws);

  const int Btot = in_sizes[0] / (T * F);   // 131072
  const int grid = Btot / R;                // 2048
  caurec<<<grid, 512, 0, stream>>>(x, cs, fc1b, fc2b, b0i, b0h, b1i, b1h,
                                   d1w, d1b, d2w, d2b, ws, (float*)d_out);
}